// Round 1
// baseline (552.642 us; speedup 1.0000x reference)
//
#include <hip/hip_runtime.h>
#include <math.h>

#define VSZ 50257
#define HSZ 1024
#define LSZ 2048

// ---------------- prep: emb0 lookup, build cat_eh = [emb0|h0], joined[0:H]=emb0
__global__ void k_prep(const int* __restrict__ din, const float* __restrict__ emb,
                       const float* __restrict__ h0, float* __restrict__ cat_eh,
                       float* __restrict__ joined) {
  int t = threadIdx.x;  // 1024
  float e = emb[(size_t)din[0] * HSZ + t];
  cat_eh[t] = e;
  cat_eh[HSZ + t] = h0[t];
  joined[t] = e;
}

// ---------------- generic wave-per-row GEMV: y[r] = dot(W[r,:K], x) + b[r]
template <int K, bool RELU>
__global__ void k_gemv(const float* __restrict__ W, const float* __restrict__ x,
                       const float* __restrict__ bias, float* __restrict__ y, int nrows) {
  int gw = (blockIdx.x * blockDim.x + threadIdx.x) >> 6;
  int lane = threadIdx.x & 63;
  if (gw >= nrows) return;
  const float4* row = (const float4*)(W + (size_t)gw * K);
  const float4* xv = (const float4*)x;
  float s = 0.f;
#pragma unroll
  for (int j = 0; j < K / 256; ++j) {
    float4 a = row[lane + 64 * j];
    float4 b = xv[lane + 64 * j];
    s += a.x * b.x + a.y * b.y + a.z * b.z + a.w * b.w;
  }
#pragma unroll
  for (int o = 32; o > 0; o >>= 1) s += __shfl_down(s, o, 64);
  if (lane == 0) {
    float r = s + bias[gw];
    if (RELU) r = fmaxf(r, 0.f);
    y[gw] = r;
  }
}

// ---------------- softmax over 2048 (one block)
__global__ void k_softmax2048(float* __restrict__ a) {
  __shared__ float sh[256];
  int t = threadIdx.x;
  float m = -1e30f;
  for (int i = t; i < LSZ; i += 256) m = fmaxf(m, a[i]);
  sh[t] = m; __syncthreads();
  for (int s = 128; s > 0; s >>= 1) { if (t < s) sh[t] = fmaxf(sh[t], sh[t + s]); __syncthreads(); }
  float gm = sh[0]; __syncthreads();
  float sum = 0.f;
  for (int i = t; i < LSZ; i += 256) { float e = expf(a[i] - gm); a[i] = e; sum += e; }
  sh[t] = sum; __syncthreads();
  for (int s = 128; s > 0; s >>= 1) { if (t < s) sh[t] += sh[t + s]; __syncthreads(); }
  float inv = 1.f / sh[0];
  for (int i = t; i < LSZ; i += 256) a[i] *= inv;
}

// ---------------- attn_applied[h] += sum_m w[m]*enc[m,h]  (grid: 4 x 32)
__global__ void k_attn_apply(const float* __restrict__ w, const float* __restrict__ enc,
                             float* __restrict__ acc) {
  int h = blockIdx.x * 256 + threadIdx.x;
  int m0 = blockIdx.y * 64;
  float s = 0.f;
  for (int m = m0; m < m0 + 64; ++m) s = fmaf(w[m], enc[(size_t)m * HSZ + h], s);
  atomicAdd(&acc[h], s);
}

// ---------------- fused gi/gh GEMV: rows 0..3071 -> gi (W_ih @ rnn_in), 3072..6143 -> gh (W_hh @ h0)
__global__ void k_gates(const float* __restrict__ Wih, const float* __restrict__ bih,
                        const float* __restrict__ xin, const float* __restrict__ Whh,
                        const float* __restrict__ bhh, const float* __restrict__ h0,
                        float* __restrict__ y) {
  int gw = (blockIdx.x * blockDim.x + threadIdx.x) >> 6;
  int lane = threadIdx.x & 63;
  const float* W; const float* x; float bv; int r;
  if (gw < 3 * HSZ) { W = Wih; x = xin; r = gw; bv = bih[r]; }
  else              { W = Whh; x = h0;  r = gw - 3 * HSZ; bv = bhh[r]; }
  const float4* row = (const float4*)(W + (size_t)r * HSZ);
  const float4* xv = (const float4*)x;
  float s = 0.f;
#pragma unroll
  for (int j = 0; j < 4; ++j) {
    float4 a = row[lane + 64 * j];
    float4 b = xv[lane + 64 * j];
    s += a.x * b.x + a.y * b.y + a.z * b.z + a.w * b.w;
  }
#pragma unroll
  for (int o = 32; o > 0; o >>= 1) s += __shfl_down(s, o, 64);
  if (lane == 0) y[gw] = s + bv;
}

// ---------------- GRU cell; writes h_new to ws and out[V..V+H); zeroes final_weights region
__global__ void k_gru(const float* __restrict__ gi, const float* __restrict__ gh,
                      const float* __restrict__ h0, float* __restrict__ h_new,
                      float* __restrict__ out) {
  int t = blockIdx.x * 256 + threadIdx.x;  // < 1024
  float r = 1.f / (1.f + expf(-(gi[t] + gh[t])));
  float z = 1.f / (1.f + expf(-(gi[HSZ + t] + gh[HSZ + t])));
  float n = tanhf(gi[2 * HSZ + t] + r * gh[2 * HSZ + t]);
  float hn = (1.f - z) * n + z * h0[t];
  h_new[t] = hn;
  out[VSZ + t] = hn;
  out[VSZ + HSZ + t] = 0.f;
}

// ---------------- copy-score GEMM: score_c[l] += sum_h tanh(enc[l,:]@Wc[h,:] + bc[h]) * h0[h]
// block tile 128(l) x 64(h), BK=32, 256 threads, thread tile 8x4. grid (16,16).
__global__ __launch_bounds__(256) void k_copy_gemm(
    const float* __restrict__ enc, const float* __restrict__ Wc,
    const float* __restrict__ bc, const float* __restrict__ hvec,
    float* __restrict__ score_c) {
  __shared__ float As[32][128];  // [k][l]
  __shared__ float Bs[32][64];   // [k][h]
  __shared__ float rs[128][17];
  int lt = blockIdx.x;  // l tile
  int ht = blockIdx.y;  // h tile
  int tid = threadIdx.x;
  int tx = tid & 15, ty = tid >> 4;
  const int l0 = lt * 128, h0r = ht * 64;
  float acc[8][4] = {};
  for (int kb = 0; kb < HSZ; kb += 32) {
    __syncthreads();
#pragma unroll
    for (int i = 0; i < 4; ++i) {
      int fi = tid + 256 * i;  // [0,1024) float4s of A tile
      int l = fi >> 3, kq = fi & 7;
      float4 v = *(const float4*)&enc[(size_t)(l0 + l) * HSZ + kb + kq * 4];
      As[kq * 4 + 0][l] = v.x; As[kq * 4 + 1][l] = v.y;
      As[kq * 4 + 2][l] = v.z; As[kq * 4 + 3][l] = v.w;
    }
#pragma unroll
    for (int i = 0; i < 2; ++i) {
      int fi = tid + 256 * i;  // [0,512) float4s of B tile
      int h = fi >> 3, kq = fi & 7;
      float4 v = *(const float4*)&Wc[(size_t)(h0r + h) * HSZ + kb + kq * 4];
      Bs[kq * 4 + 0][h] = v.x; Bs[kq * 4 + 1][h] = v.y;
      Bs[kq * 4 + 2][h] = v.z; Bs[kq * 4 + 3][h] = v.w;
    }
    __syncthreads();
#pragma unroll
    for (int k = 0; k < 32; ++k) {
      float4 b4 = *(const float4*)&Bs[k][tx * 4];
      float4 a0 = *(const float4*)&As[k][ty * 8];
      float4 a1 = *(const float4*)&As[k][ty * 8 + 4];
      float av[8] = {a0.x, a0.y, a0.z, a0.w, a1.x, a1.y, a1.z, a1.w};
      float bv[4] = {b4.x, b4.y, b4.z, b4.w};
#pragma unroll
      for (int i = 0; i < 8; ++i)
#pragma unroll
        for (int j = 0; j < 4; ++j) acc[i][j] = fmaf(av[i], bv[j], acc[i][j]);
    }
  }
  float hw[4], bcv[4];
#pragma unroll
  for (int j = 0; j < 4; ++j) {
    int h = h0r + tx * 4 + j;
    bcv[j] = bc[h];
    hw[j] = hvec[h];
  }
  __syncthreads();
#pragma unroll
  for (int i = 0; i < 8; ++i) {
    float p = 0.f;
#pragma unroll
    for (int j = 0; j < 4; ++j) p += tanhf(acc[i][j] + bcv[j]) * hw[j];
    rs[ty * 8 + i][tx] = p;
  }
  __syncthreads();
  if (tid < 128) {
    float s = 0.f;
#pragma unroll
    for (int x = 0; x < 16; ++x) s += rs[tid][x];
    atomicAdd(&score_c[l0 + tid], s);
  }
}

// ---------------- softmax over 52305 = V + L : partial max
__global__ void k_pmax(const float* __restrict__ score, float* __restrict__ pmax) {
  __shared__ float sh[256];
  int t = threadIdx.x, b = blockIdx.x;
  float m = -1e30f;
  for (int i = b * 256 + t; i < VSZ + LSZ; i += 64 * 256) m = fmaxf(m, score[i]);
  sh[t] = m; __syncthreads();
  for (int s = 128; s > 0; s >>= 1) { if (t < s) sh[t] = fmaxf(sh[t], sh[t + s]); __syncthreads(); }
  if (t == 0) pmax[b] = sh[0];
}

// ---------------- partial sums of exp (reduces pmax in-block first)
__global__ void k_psum(const float* __restrict__ score, const float* __restrict__ pmax,
                       float* __restrict__ psum) {
  __shared__ float shg;
  __shared__ float sh[256];
  int t = threadIdx.x, b = blockIdx.x;
  if (t < 64) {
    float m = pmax[t];
    for (int o = 1; o < 64; o <<= 1) m = fmaxf(m, __shfl_xor(m, o, 64));
    if (t == 0) shg = m;
  }
  __syncthreads();
  float gmax = shg;
  float s = 0.f;
  for (int i = b * 256 + t; i < VSZ + LSZ; i += 64 * 256) s += expf(score[i] - gmax);
  sh[t] = s; __syncthreads();
  for (int s2 = 128; s2 > 0; s2 >>= 1) { if (t < s2) sh[t] += sh[t + s2]; __syncthreads(); }
  if (t == 0) psum[b] = sh[0];
}

// ---------------- final prob_g write
__global__ void k_final_g(const float* __restrict__ score, const float* __restrict__ pmax,
                          const float* __restrict__ psum, float* __restrict__ out) {
  __shared__ float r2[2];
  int t = threadIdx.x;
  if (t < 64) {
    float m = pmax[t], s = psum[t];
    for (int o = 1; o < 64; o <<= 1) {
      m = fmaxf(m, __shfl_xor(m, o, 64));
      s += __shfl_xor(s, o, 64);
    }
    if (t == 0) { r2[0] = m; r2[1] = 1.f / s; }
  }
  __syncthreads();
  float gmax = r2[0], inv = r2[1];
  int v = blockIdx.x * 256 + t;
  if (v < VSZ) out[v] = expf(score[v] - gmax) * inv;
}

// ---------------- prob_c: scatter-add into out[0..V), matched rows into final_weights
__global__ void k_final_c(const float* __restrict__ score, const float* __restrict__ pmax,
                          const float* __restrict__ psum, const int* __restrict__ idx,
                          const int* __restrict__ din, const float* __restrict__ enc,
                          float* __restrict__ out) {
  __shared__ float r2[2];
  int t = threadIdx.x;
  if (t < 64) {
    float m = pmax[t], s = psum[t];
    for (int o = 1; o < 64; o <<= 1) {
      m = fmaxf(m, __shfl_xor(m, o, 64));
      s += __shfl_xor(s, o, 64);
    }
    if (t == 0) { r2[0] = m; r2[1] = 1.f / s; }
  }
  __syncthreads();
  float gmax = r2[0], inv = r2[1];
  int l = blockIdx.x * 256 + t;  // < 2048
  float p = expf(score[VSZ + l] - gmax) * inv;
  atomicAdd(&out[idx[l]], p);
  if (idx[l] == din[0]) {
    for (int h = 0; h < HSZ; ++h)
      atomicAdd(&out[VSZ + HSZ + h], p * enc[(size_t)l * HSZ + h]);
  }
}

extern "C" void kernel_launch(void* const* d_in, const int* in_sizes, int n_in,
                              void* d_out, int out_size, void* d_ws, size_t ws_size,
                              hipStream_t stream) {
  const int*   din = (const int*)d_in[0];
  const float* h0  = (const float*)d_in[1];
  const float* enc = (const float*)d_in[2];
  const int*   idx = (const int*)d_in[3];
  const float* emb = (const float*)d_in[4];
  const float* Waw = (const float*)d_in[5];
  const float* baw = (const float*)d_in[6];
  const float* Wau = (const float*)d_in[7];
  const float* bau = (const float*)d_in[8];
  const float* Wih = (const float*)d_in[9];
  const float* bih = (const float*)d_in[10];
  const float* Whh = (const float*)d_in[11];
  const float* bhh = (const float*)d_in[12];
  const float* Wc  = (const float*)d_in[13];
  const float* bc  = (const float*)d_in[14];
  const float* Wg  = (const float*)d_in[15];
  const float* bg  = (const float*)d_in[16];
  float* out = (float*)d_out;
  float* ws  = (float*)d_ws;

  // ws layout (floats):
  float* cat_eh = ws;           // 2048
  float* joined = ws + 2048;    // 2048  [emb0 | attn_applied(acc)]
  float* rnn_in = ws + 4096;    // 1024
  float* gi     = ws + 5120;    // 3072, gh follows contiguously
  float* gh     = ws + 8192;    // 3072
  float* h_new  = ws + 11264;   // 1024
  float* attnw  = ws + 12288;   // 2048
  float* score  = ws + 14336;   // 52305 = [score_g | score_c]
  float* pmax   = ws + 66656;   // 64
  float* psum   = ws + 66720;   // 64
  // total 66784 floats ~= 261 KB

  // zero the two accumulation regions (re-poisoned to 0xAA before every call)
  hipMemsetAsync(joined + HSZ, 0, HSZ * sizeof(float), stream);
  hipMemsetAsync(score + VSZ, 0, LSZ * sizeof(float), stream);

  k_prep<<<1, 1024, 0, stream>>>(din, emb, h0, cat_eh, joined);
  k_gemv<2048, false><<<512, 256, 0, stream>>>(Waw, cat_eh, baw, attnw, LSZ);
  k_softmax2048<<<1, 256, 0, stream>>>(attnw);
  k_attn_apply<<<dim3(4, 32), 256, 0, stream>>>(attnw, enc, joined + HSZ);
  k_gemv<2048, true><<<256, 256, 0, stream>>>(Wau, joined, bau, rnn_in, HSZ);
  k_gates<<<1536, 256, 0, stream>>>(Wih, bih, rnn_in, Whh, bhh, h0, gi);
  k_gru<<<4, 256, 0, stream>>>(gi, gh, h0, h_new, out);
  // independent copy-score GEMM (uses OLD h0, not h_new)
  k_copy_gemm<<<dim3(16, 16), 256, 0, stream>>>(enc, Wc, bc, h0, score + VSZ);
  // vocab projection (the big one: 206 MB)
  k_gemv<1024, false><<<(VSZ + 3) / 4, 256, 0, stream>>>(Wg, h_new, bg, score, VSZ);
  // joint softmax over V+L
  k_pmax<<<64, 256, 0, stream>>>(score, pmax);
  k_psum<<<64, 256, 0, stream>>>(score, pmax, psum);
  k_final_g<<<(VSZ + 255) / 256, 256, 0, stream>>>(score, pmax, psum, out);
  k_final_c<<<LSZ / 256, 256, 0, stream>>>(score, pmax, psum, idx, din, enc, out);
}

// Round 2
// 515.951 us; speedup vs baseline: 1.0711x; 1.0711x over previous
//
#include <hip/hip_runtime.h>
#include <math.h>

#define VSZ 50257
#define HSZ 1024
#define LSZ 2048
#define SHIFT 60.0f

// ============ K1: attention GEMV (rows of W_attn_w vs [emb0|h0]) + all zero-init ============
// blocks 0..511: 4 rows/block of attnw. blocks 512..708: zero out[0..V).
// block 709: zero score_c. block 710: zero acc + psum.
__global__ void k_attn(const float* __restrict__ Waw, const float* __restrict__ baw,
                       const int* __restrict__ din, const float* __restrict__ emb,
                       const float* __restrict__ h0, float* __restrict__ attnw,
                       float* __restrict__ out, float* __restrict__ score_c,
                       float* __restrict__ acc, float* __restrict__ psum) {
  int bid = blockIdx.x, tid = threadIdx.x;
  if (bid < 512) {
    int gw = bid * 4 + (tid >> 6);
    int lane = tid & 63;
    const float4* row = (const float4*)(Waw + (size_t)gw * 2048);
    const float4* e4 = (const float4*)(emb + (size_t)din[0] * HSZ);
    const float4* h4 = (const float4*)h0;
    float s = 0.f;
#pragma unroll
    for (int j = 0; j < 4; ++j) {
      float4 a = row[lane + 64 * j];
      float4 b = e4[lane + 64 * j];
      s += a.x * b.x + a.y * b.y + a.z * b.z + a.w * b.w;
    }
#pragma unroll
    for (int j = 0; j < 4; ++j) {
      float4 a = row[256 + lane + 64 * j];
      float4 b = h4[lane + 64 * j];
      s += a.x * b.x + a.y * b.y + a.z * b.z + a.w * b.w;
    }
#pragma unroll
    for (int o = 32; o > 0; o >>= 1) s += __shfl_down(s, o, 64);
    if (lane == 0) attnw[gw] = s + baw[gw];
  } else if (bid < 709) {
    int v = (bid - 512) * 256 + tid;
    if (v < VSZ) out[v] = 0.f;
  } else if (bid == 709) {
#pragma unroll
    for (int k = 0; k < 8; ++k) score_c[tid + 256 * k] = 0.f;
  } else {
#pragma unroll
    for (int k = 0; k < 4; ++k) acc[tid + 256 * k] = 0.f;
    if (tid == 0) psum[0] = 0.f;
  }
}

// ============ K2: in-block softmax(attnw) + attn_applied accumulate ============
// grid 128: hb = bid&3 (256 h), mb = bid>>2 (64 m)
__global__ void k_attn_apply(const float* __restrict__ attnw, const float* __restrict__ enc,
                             float* __restrict__ acc) {
  __shared__ float red[256];
  __shared__ float sw[64];
  int bid = blockIdx.x, t = threadIdx.x;
  int hb = bid & 3, mb = bid >> 2;
  float m = -1e30f;
  for (int i = t; i < LSZ; i += 256) m = fmaxf(m, attnw[i]);
  red[t] = m; __syncthreads();
  for (int s = 128; s > 0; s >>= 1) { if (t < s) red[t] = fmaxf(red[t], red[t + s]); __syncthreads(); }
  float gmax = red[0]; __syncthreads();
  float sum = 0.f;
  for (int i = t; i < LSZ; i += 256) sum += expf(attnw[i] - gmax);
  red[t] = sum; __syncthreads();
  for (int s = 128; s > 0; s >>= 1) { if (t < s) red[t] += red[t + s]; __syncthreads(); }
  float inv = 1.f / red[0];
  if (t < 64) sw[t] = expf(attnw[mb * 64 + t] - gmax) * inv;
  __syncthreads();
  int h = hb * 256 + t;
  float s = 0.f;
#pragma unroll 4
  for (int j = 0; j < 64; ++j) s = fmaf(sw[j], enc[(size_t)(mb * 64 + j) * HSZ + h], s);
  atomicAdd(&acc[h], s);
}

// ============ K3: rnn_in = relu(W_attn_u @ [emb0|attn_applied] + b) ============
__global__ void k_rnn(const float* __restrict__ Wau, const float* __restrict__ bau,
                      const int* __restrict__ din, const float* __restrict__ emb,
                      const float* __restrict__ acc, float* __restrict__ rnn_in) {
  int gw = blockIdx.x * 4 + (threadIdx.x >> 6);
  int lane = threadIdx.x & 63;
  const float4* row = (const float4*)(Wau + (size_t)gw * 2048);
  const float4* e4 = (const float4*)(emb + (size_t)din[0] * HSZ);
  const float4* a4 = (const float4*)acc;
  float s = 0.f;
#pragma unroll
  for (int j = 0; j < 4; ++j) {
    float4 a = row[lane + 64 * j];
    float4 b = e4[lane + 64 * j];
    s += a.x * b.x + a.y * b.y + a.z * b.z + a.w * b.w;
  }
#pragma unroll
  for (int j = 0; j < 4; ++j) {
    float4 a = row[256 + lane + 64 * j];
    float4 b = a4[lane + 64 * j];
    s += a.x * b.x + a.y * b.y + a.z * b.z + a.w * b.w;
  }
#pragma unroll
  for (int o = 32; o > 0; o >>= 1) s += __shfl_down(s, o, 64);
  if (lane == 0) rnn_in[gw] = fmaxf(s + bau[gw], 0.f);
}

// ============ K4: gi/gh gates (6144 rows) ============
__global__ void k_gates(const float* __restrict__ Wih, const float* __restrict__ bih,
                        const float* __restrict__ xin, const float* __restrict__ Whh,
                        const float* __restrict__ bhh, const float* __restrict__ h0,
                        float* __restrict__ y) {
  int gw = blockIdx.x * 4 + (threadIdx.x >> 6);
  int lane = threadIdx.x & 63;
  const float* W; const float* x; float bv; int r;
  if (gw < 3 * HSZ) { W = Wih; x = xin; r = gw; bv = bih[r]; }
  else              { W = Whh; x = h0;  r = gw - 3 * HSZ; bv = bhh[r]; }
  const float4* row = (const float4*)(W + (size_t)r * HSZ);
  const float4* xv = (const float4*)x;
  float s = 0.f;
#pragma unroll
  for (int j = 0; j < 4; ++j) {
    float4 a = row[lane + 64 * j];
    float4 b = xv[lane + 64 * j];
    s += a.x * b.x + a.y * b.y + a.z * b.z + a.w * b.w;
  }
#pragma unroll
  for (int o = 32; o > 0; o >>= 1) s += __shfl_down(s, o, 64);
  if (lane == 0) y[gw] = s + bv;
}

// ============ K5: GRU cell; writes h_new, out[V..V+H), zeroes final_weights ============
__global__ void k_gru(const float* __restrict__ gi, const float* __restrict__ gh,
                      const float* __restrict__ h0, float* __restrict__ h_new,
                      float* __restrict__ out) {
  int t = blockIdx.x * 256 + threadIdx.x;  // < 1024
  float r = 1.f / (1.f + expf(-(gi[t] + gh[t])));
  float z = 1.f / (1.f + expf(-(gi[HSZ + t] + gh[HSZ + t])));
  float n = tanhf(gi[2 * HSZ + t] + r * gh[2 * HSZ + t]);
  float hn = (1.f - z) * n + z * h0[t];
  h_new[t] = hn;
  out[VSZ + t] = hn;
  out[VSZ + HSZ + t] = 0.f;
}

// ============ K6: fused vocab GEMV + copy-score GEMM ============
// blocks 0..255: GEMM tiles (16 l-tiles x 16 h-tiles, 128x64, BK=32, 8x4/thread)
// blocks 256..: vocab GEMV, 4 rows/block
__global__ __launch_bounds__(256) void k_big(
    const float* __restrict__ enc, const float* __restrict__ Wc,
    const float* __restrict__ bc, const float* __restrict__ hvec,
    const float* __restrict__ Wg, const float* __restrict__ bg,
    const float* __restrict__ h_new, float* __restrict__ score) {
  __shared__ float As[32][128];  // aliased as rs[128][17] in epilogue
  __shared__ float Bs[32][64];
  int bid = blockIdx.x, tid = threadIdx.x;
  if (bid < 256) {
    int lt = bid & 15, ht = bid >> 4;
    int tx = tid & 15, ty = tid >> 4;
    const int l0 = lt * 128, h0r = ht * 64;
    float acc[8][4] = {};
    for (int kb = 0; kb < HSZ; kb += 32) {
      __syncthreads();
#pragma unroll
      for (int i = 0; i < 4; ++i) {
        int fi = tid + 256 * i;
        int l = fi >> 3, kq = fi & 7;
        float4 v = *(const float4*)&enc[(size_t)(l0 + l) * HSZ + kb + kq * 4];
        As[kq * 4 + 0][l] = v.x; As[kq * 4 + 1][l] = v.y;
        As[kq * 4 + 2][l] = v.z; As[kq * 4 + 3][l] = v.w;
      }
#pragma unroll
      for (int i = 0; i < 2; ++i) {
        int fi = tid + 256 * i;
        int h = fi >> 3, kq = fi & 7;
        float4 v = *(const float4*)&Wc[(size_t)(h0r + h) * HSZ + kb + kq * 4];
        Bs[kq * 4 + 0][h] = v.x; Bs[kq * 4 + 1][h] = v.y;
        Bs[kq * 4 + 2][h] = v.z; Bs[kq * 4 + 3][h] = v.w;
      }
      __syncthreads();
#pragma unroll
      for (int k = 0; k < 32; ++k) {
        float4 b4 = *(const float4*)&Bs[k][tx * 4];
        float4 a0 = *(const float4*)&As[k][ty * 8];
        float4 a1 = *(const float4*)&As[k][ty * 8 + 4];
        float av[8] = {a0.x, a0.y, a0.z, a0.w, a1.x, a1.y, a1.z, a1.w};
        float bv[4] = {b4.x, b4.y, b4.z, b4.w};
#pragma unroll
        for (int i = 0; i < 8; ++i)
#pragma unroll
          for (int j = 0; j < 4; ++j) acc[i][j] = fmaf(av[i], bv[j], acc[i][j]);
      }
    }
    float hw[4], bcv[4];
#pragma unroll
    for (int j = 0; j < 4; ++j) {
      int h = h0r + tx * 4 + j;
      bcv[j] = bc[h];
      hw[j] = hvec[h];
    }
    __syncthreads();
    float (*rs)[17] = (float (*)[17])&As[0][0];  // 128*17 = 2176 <= 4096 floats
#pragma unroll
    for (int i = 0; i < 8; ++i) {
      float p = 0.f;
#pragma unroll
      for (int j = 0; j < 4; ++j) p += tanhf(acc[i][j] + bcv[j]) * hw[j];
      rs[ty * 8 + i][tx] = p;
    }
    __syncthreads();
    if (tid < 128) {
      float s = 0.f;
#pragma unroll
      for (int x = 0; x < 16; ++x) s += rs[tid][x];
      atomicAdd(&score[VSZ + l0 + tid], s);
    }
  } else {
    int gw = (bid - 256) * 4 + (tid >> 6);
    int lane = tid & 63;
    if (gw >= VSZ) return;
    const float4* row = (const float4*)(Wg + (size_t)gw * HSZ);
    const float4* xv = (const float4*)h_new;
    float s = 0.f;
#pragma unroll
    for (int j = 0; j < 4; ++j) {
      float4 a = row[lane + 64 * j];
      float4 b = xv[lane + 64 * j];
      s += a.x * b.x + a.y * b.y + a.z * b.z + a.w * b.w;
    }
#pragma unroll
    for (int o = 32; o > 0; o >>= 1) s += __shfl_down(s, o, 64);
    if (lane == 0) score[gw] = s + bg[gw];
  }
}

// ============ K7: global exp-sum with fixed shift (softmax denom) ============
__global__ void k_sum(const float* __restrict__ score, float* __restrict__ psum) {
  __shared__ float sh[256];
  int t = threadIdx.x, b = blockIdx.x;
  float s = 0.f;
  for (int i = b * 256 + t; i < VSZ + LSZ; i += 64 * 256) s += expf(score[i] - SHIFT);
  sh[t] = s; __syncthreads();
  for (int s2 = 128; s2 > 0; s2 >>= 1) { if (t < s2) sh[t] += sh[t + s2]; __syncthreads(); }
  if (t == 0) atomicAdd(psum, sh[0]);
}

// ============ K8: final probs (g scatter + c scatter + matched weights) ============
// blocks 0..196: prob_g atomicAdd into pre-zeroed out. blocks 197..204: prob_c part.
__global__ void k_final(const float* __restrict__ score, const float* __restrict__ psum,
                        const int* __restrict__ idx, const int* __restrict__ din,
                        const float* __restrict__ enc, float* __restrict__ out) {
  int bid = blockIdx.x, t = threadIdx.x;
  float inv = 1.f / psum[0];
  if (bid < 197) {
    int v = bid * 256 + t;
    if (v < VSZ) atomicAdd(&out[v], expf(score[v] - SHIFT) * inv);
  } else {
    __shared__ float pm[256];
    __shared__ int flag;
    if (t == 0) flag = 0;
    __syncthreads();
    int l0 = (bid - 197) * 256;
    int l = l0 + t;
    float p = expf(score[VSZ + l] - SHIFT) * inv;
    atomicAdd(&out[idx[l]], p);
    int matched = (idx[l] == din[0]);
    pm[t] = matched ? p : 0.f;
    if (matched) atomicExch(&flag, 1);
    __syncthreads();
    if (flag) {
      for (int h = t; h < HSZ; h += 256) {
        float s = 0.f;
        for (int l2 = 0; l2 < 256; ++l2)
          if (pm[l2] != 0.f) s = fmaf(pm[l2], enc[(size_t)(l0 + l2) * HSZ + h], s);
        if (s != 0.f) atomicAdd(&out[VSZ + HSZ + h], s);
      }
    }
  }
}

extern "C" void kernel_launch(void* const* d_in, const int* in_sizes, int n_in,
                              void* d_out, int out_size, void* d_ws, size_t ws_size,
                              hipStream_t stream) {
  const int*   din = (const int*)d_in[0];
  const float* h0  = (const float*)d_in[1];
  const float* enc = (const float*)d_in[2];
  const int*   idx = (const int*)d_in[3];
  const float* emb = (const float*)d_in[4];
  const float* Waw = (const float*)d_in[5];
  const float* baw = (const float*)d_in[6];
  const float* Wau = (const float*)d_in[7];
  const float* bau = (const float*)d_in[8];
  const float* Wih = (const float*)d_in[9];
  const float* bih = (const float*)d_in[10];
  const float* Whh = (const float*)d_in[11];
  const float* bhh = (const float*)d_in[12];
  const float* Wc  = (const float*)d_in[13];
  const float* bc  = (const float*)d_in[14];
  const float* Wg  = (const float*)d_in[15];
  const float* bg  = (const float*)d_in[16];
  float* out = (float*)d_out;
  float* ws  = (float*)d_ws;

  // ws layout (floats), all 16B-aligned:
  float* acc    = ws;           // 1024 (attn_applied accumulator)
  float* rnn_in = ws + 1024;    // 1024
  float* gi     = ws + 2048;    // 3072
  float* gh     = ws + 5120;    // 3072
  float* h_new  = ws + 8192;    // 1024
  float* attnw  = ws + 9216;    // 2048
  float* score  = ws + 11264;   // 52305 = [score_g | score_c]
  float* psum   = ws + 63576;   // 1

  k_attn<<<711, 256, 0, stream>>>(Waw, baw, din, emb, h0, attnw, out, score + VSZ, acc, psum);
  k_attn_apply<<<128, 256, 0, stream>>>(attnw, enc, acc);
  k_rnn<<<256, 256, 0, stream>>>(Wau, bau, din, emb, acc, rnn_in);
  k_gates<<<1536, 256, 0, stream>>>(Wih, bih, rnn_in, Whh, bhh, h0, gi);
  k_gru<<<4, 256, 0, stream>>>(gi, gh, h0, h_new, out);
  k_big<<<256 + (VSZ + 3) / 4, 256, 0, stream>>>(enc, Wc, bc, h0, Wg, bg, h_new, score);
  k_sum<<<64, 256, 0, stream>>>(score, psum);
  k_final<<<205, 256, 0, stream>>>(score, psum, idx, din, enc, out);
}

// Round 3
// 463.468 us; speedup vs baseline: 1.1924x; 1.1132x over previous
//
#include <hip/hip_runtime.h>
#include <math.h>

#define VSZ 50257
#define HSZ 1024
#define LSZ 2048
#define SHIFT 60.0f

typedef __attribute__((ext_vector_type(8))) short bf16x8;
typedef __attribute__((ext_vector_type(4))) float f32x4;

__device__ __forceinline__ unsigned short f2bf(float f) {
  unsigned int u = __float_as_uint(f);
  u += 0x7FFFu + ((u >> 16) & 1u);  // RNE
  return (unsigned short)(u >> 16);
}

// ============ K1: attention GEMV + zero-init + fp32->bf16 conversion ============
// blocks 0..511: attnw GEMV (4 rows/block). 512..708: zero out[0..V).
// 709: zero score_c. 710: zero acc+psum. 711..1478: convert enc|Wc to bf16.
__global__ void k_attn(const float* __restrict__ Waw, const float* __restrict__ baw,
                       const int* __restrict__ din, const float* __restrict__ emb,
                       const float* __restrict__ h0, const float* __restrict__ enc,
                       const float* __restrict__ Wc, float* __restrict__ attnw,
                       float* __restrict__ out, float* __restrict__ score_c,
                       float* __restrict__ acc, float* __restrict__ psum,
                       unsigned short* __restrict__ bfbuf) {
  int bid = blockIdx.x, tid = threadIdx.x;
  if (bid < 512) {
    int gw = bid * 4 + (tid >> 6);
    int lane = tid & 63;
    const float4* row = (const float4*)(Waw + (size_t)gw * 2048);
    const float4* e4 = (const float4*)(emb + (size_t)din[0] * HSZ);
    const float4* h4 = (const float4*)h0;
    float s = 0.f;
#pragma unroll
    for (int j = 0; j < 4; ++j) {
      float4 a = row[lane + 64 * j];
      float4 b = e4[lane + 64 * j];
      s += a.x * b.x + a.y * b.y + a.z * b.z + a.w * b.w;
    }
#pragma unroll
    for (int j = 0; j < 4; ++j) {
      float4 a = row[256 + lane + 64 * j];
      float4 b = h4[lane + 64 * j];
      s += a.x * b.x + a.y * b.y + a.z * b.z + a.w * b.w;
    }
#pragma unroll
    for (int o = 32; o > 0; o >>= 1) s += __shfl_down(s, o, 64);
    if (lane == 0) attnw[gw] = s + baw[gw];
  } else if (bid < 709) {
    int v = (bid - 512) * 256 + tid;
    if (v < VSZ) out[v] = 0.f;
  } else if (bid == 709) {
#pragma unroll
    for (int k = 0; k < 8; ++k) score_c[tid + 256 * k] = 0.f;
  } else if (bid == 710) {
#pragma unroll
    for (int k = 0; k < 4; ++k) acc[tid + 256 * k] = 0.f;
    if (tid == 0) psum[0] = 0.f;
  } else {
    // conversion: 768 blocks x 256 threads x 4 float4 = 786432 float4s
    // first 524288 float4 from enc, then 262144 from Wc
    int cb = bid - 711;
#pragma unroll
    for (int c = 0; c < 4; ++c) {
      int g = cb * 1024 + c * 256 + tid;
      float4 v;
      if (g < 524288) v = ((const float4*)enc)[g];
      else            v = ((const float4*)Wc)[g - 524288];
      ushort4 o;
      o.x = f2bf(v.x); o.y = f2bf(v.y); o.z = f2bf(v.z); o.w = f2bf(v.w);
      *(ushort4*)(bfbuf + (size_t)g * 4) = o;
    }
  }
}

// ============ K2: in-block softmax(attnw) + attn_applied accumulate ============
__global__ void k_attn_apply(const float* __restrict__ attnw, const float* __restrict__ enc,
                             float* __restrict__ acc) {
  __shared__ float red[256];
  __shared__ float sw[64];
  int bid = blockIdx.x, t = threadIdx.x;
  int hb = bid & 3, mb = bid >> 2;
  float m = -1e30f;
  for (int i = t; i < LSZ; i += 256) m = fmaxf(m, attnw[i]);
  red[t] = m; __syncthreads();
  for (int s = 128; s > 0; s >>= 1) { if (t < s) red[t] = fmaxf(red[t], red[t + s]); __syncthreads(); }
  float gmax = red[0]; __syncthreads();
  float sum = 0.f;
  for (int i = t; i < LSZ; i += 256) sum += expf(attnw[i] - gmax);
  red[t] = sum; __syncthreads();
  for (int s = 128; s > 0; s >>= 1) { if (t < s) red[t] += red[t + s]; __syncthreads(); }
  float inv = 1.f / red[0];
  if (t < 64) sw[t] = expf(attnw[mb * 64 + t] - gmax) * inv;
  __syncthreads();
  int h = hb * 256 + t;
  float s = 0.f;
#pragma unroll 4
  for (int j = 0; j < 64; ++j) s = fmaf(sw[j], enc[(size_t)(mb * 64 + j) * HSZ + h], s);
  atomicAdd(&acc[h], s);
}

// ============ K3: rnn_in = relu(W_attn_u @ [emb0|attn_applied] + b) ============
__global__ void k_rnn(const float* __restrict__ Wau, const float* __restrict__ bau,
                      const int* __restrict__ din, const float* __restrict__ emb,
                      const float* __restrict__ acc, float* __restrict__ rnn_in) {
  int gw = blockIdx.x * 4 + (threadIdx.x >> 6);
  int lane = threadIdx.x & 63;
  const float4* row = (const float4*)(Wau + (size_t)gw * 2048);
  const float4* e4 = (const float4*)(emb + (size_t)din[0] * HSZ);
  const float4* a4 = (const float4*)acc;
  float s = 0.f;
#pragma unroll
  for (int j = 0; j < 4; ++j) {
    float4 a = row[lane + 64 * j];
    float4 b = e4[lane + 64 * j];
    s += a.x * b.x + a.y * b.y + a.z * b.z + a.w * b.w;
  }
#pragma unroll
  for (int j = 0; j < 4; ++j) {
    float4 a = row[256 + lane + 64 * j];
    float4 b = a4[lane + 64 * j];
    s += a.x * b.x + a.y * b.y + a.z * b.z + a.w * b.w;
  }
#pragma unroll
  for (int o = 32; o > 0; o >>= 1) s += __shfl_down(s, o, 64);
  if (lane == 0) rnn_in[gw] = fmaxf(s + bau[gw], 0.f);
}

// ============ K4: gi/gh gates (6144 rows) ============
__global__ void k_gates(const float* __restrict__ Wih, const float* __restrict__ bih,
                        const float* __restrict__ xin, const float* __restrict__ Whh,
                        const float* __restrict__ bhh, const float* __restrict__ h0,
                        float* __restrict__ y) {
  int gw = blockIdx.x * 4 + (threadIdx.x >> 6);
  int lane = threadIdx.x & 63;
  const float* W; const float* x; float bv; int r;
  if (gw < 3 * HSZ) { W = Wih; x = xin; r = gw; bv = bih[r]; }
  else              { W = Whh; x = h0;  r = gw - 3 * HSZ; bv = bhh[r]; }
  const float4* row = (const float4*)(W + (size_t)r * HSZ);
  const float4* xv = (const float4*)x;
  float s = 0.f;
#pragma unroll
  for (int j = 0; j < 4; ++j) {
    float4 a = row[lane + 64 * j];
    float4 b = xv[lane + 64 * j];
    s += a.x * b.x + a.y * b.y + a.z * b.z + a.w * b.w;
  }
#pragma unroll
  for (int o = 32; o > 0; o >>= 1) s += __shfl_down(s, o, 64);
  if (lane == 0) y[gw] = s + bv;
}

// ============ K5: GRU cell ============
__global__ void k_gru(const float* __restrict__ gi, const float* __restrict__ gh,
                      const float* __restrict__ h0, float* __restrict__ h_new,
                      float* __restrict__ out) {
  int t = blockIdx.x * 256 + threadIdx.x;  // < 1024
  float r = 1.f / (1.f + expf(-(gi[t] + gh[t])));
  float z = 1.f / (1.f + expf(-(gi[HSZ + t] + gh[HSZ + t])));
  float n = tanhf(gi[2 * HSZ + t] + r * gh[2 * HSZ + t]);
  float hn = (1.f - z) * n + z * h0[t];
  h_new[t] = hn;
  out[VSZ + t] = hn;
  out[VSZ + HSZ + t] = 0.f;
}

// ============ K6: fused bf16-MFMA copy GEMM + vocab GEMV (no LDS) ============
// blocks 0..511: GEMM 64x64 tiles (32 l-tiles x 16 h-tiles), frags from global bf16.
// blocks 512..: vocab GEMV, 8 rows/block (2 rows/wave), x cached in regs.
__global__ __launch_bounds__(256) void k_huge(
    const unsigned short* __restrict__ encB, const unsigned short* __restrict__ WcB,
    const float* __restrict__ bc, const float* __restrict__ hvec,
    const float* __restrict__ Wg, const float* __restrict__ bg,
    const float* __restrict__ h_new, float* __restrict__ score) {
  int bid = blockIdx.x, tid = threadIdx.x;
  int wave = tid >> 6, lane = tid & 63;
  if (bid < 512) {
    int l0 = (bid >> 4) * 64 + wave * 16;  // this wave's 16-row strip
    int h0r = (bid & 15) * 64;
    int col = lane & 15, quad = lane >> 4;
    f32x4 acc[4] = {};
    const unsigned short* arow = encB + ((size_t)(l0 + col) << 10) + quad * 8;
#pragma unroll 4
    for (int k0 = 0; k0 < HSZ; k0 += 32) {
      bf16x8 a = *(const bf16x8*)(arow + k0);
#pragma unroll
      for (int ht = 0; ht < 4; ++ht) {
        bf16x8 b = *(const bf16x8*)(WcB + ((size_t)(h0r + ht * 16 + col) << 10) + k0 + quad * 8);
        acc[ht] = __builtin_amdgcn_mfma_f32_16x16x32_bf16(a, b, acc[ht], 0, 0, 0);
      }
    }
    // epilogue: p = tanh(c + bc[h]) * h0[h], reduce over h
    float rsum[4] = {0.f, 0.f, 0.f, 0.f};
#pragma unroll
    for (int ht = 0; ht < 4; ++ht) {
      int h = h0r + ht * 16 + col;
      float bch = bc[h], hw = hvec[h];
#pragma unroll
      for (int r = 0; r < 4; ++r) rsum[r] += tanhf(acc[ht][r] + bch) * hw;
    }
#pragma unroll
    for (int o = 1; o < 16; o <<= 1) {
#pragma unroll
      for (int r = 0; r < 4; ++r) rsum[r] += __shfl_xor(rsum[r], o, 64);
    }
    if (col == 0) {
      int lrow = l0 + quad * 4;  // C/D: row = quad*4 + reg
#pragma unroll
      for (int r = 0; r < 4; ++r) atomicAdd(&score[VSZ + lrow + r], rsum[r]);
    }
  } else {
    int r0 = (bid - 512) * 8 + wave * 2;
    int ra = r0 < VSZ ? r0 : VSZ - 1;
    int rb = r0 + 1 < VSZ ? r0 + 1 : VSZ - 1;
    const float4* xv = (const float4*)h_new;
    float4 x0 = xv[lane], x1 = xv[lane + 64], x2 = xv[lane + 128], x3 = xv[lane + 192];
    const float4* p0 = (const float4*)(Wg + (size_t)ra * HSZ);
    const float4* p1 = (const float4*)(Wg + (size_t)rb * HSZ);
    float4 a0 = p0[lane], a1 = p0[lane + 64], a2 = p0[lane + 128], a3 = p0[lane + 192];
    float4 b0 = p1[lane], b1 = p1[lane + 64], b2 = p1[lane + 128], b3 = p1[lane + 192];
    float s0 = a0.x * x0.x + a0.y * x0.y + a0.z * x0.z + a0.w * x0.w
             + a1.x * x1.x + a1.y * x1.y + a1.z * x1.z + a1.w * x1.w
             + a2.x * x2.x + a2.y * x2.y + a2.z * x2.z + a2.w * x2.w
             + a3.x * x3.x + a3.y * x3.y + a3.z * x3.z + a3.w * x3.w;
    float s1 = b0.x * x0.x + b0.y * x0.y + b0.z * x0.z + b0.w * x0.w
             + b1.x * x1.x + b1.y * x1.y + b1.z * x1.z + b1.w * x1.w
             + b2.x * x2.x + b2.y * x2.y + b2.z * x2.z + b2.w * x2.w
             + b3.x * x3.x + b3.y * x3.y + b3.z * x3.z + b3.w * x3.w;
#pragma unroll
    for (int o = 32; o > 0; o >>= 1) {
      s0 += __shfl_down(s0, o, 64);
      s1 += __shfl_down(s1, o, 64);
    }
    if (lane == 0) {
      if (r0 < VSZ) score[r0] = s0 + bg[r0];
      if (r0 + 1 < VSZ) score[r0 + 1] = s1 + bg[r0 + 1];
    }
  }
}

// ============ K7: global exp-sum with fixed shift ============
__global__ void k_sum(const float* __restrict__ score, float* __restrict__ psum) {
  __shared__ float sh[256];
  int t = threadIdx.x, b = blockIdx.x;
  float s = 0.f;
  for (int i = b * 256 + t; i < VSZ + LSZ; i += 64 * 256) s += expf(score[i] - SHIFT);
  sh[t] = s; __syncthreads();
  for (int s2 = 128; s2 > 0; s2 >>= 1) { if (t < s2) sh[t] += sh[t + s2]; __syncthreads(); }
  if (t == 0) atomicAdd(psum, sh[0]);
}

// ============ K8: final probs ============
__global__ void k_final(const float* __restrict__ score, const float* __restrict__ psum,
                        const int* __restrict__ idx, const int* __restrict__ din,
                        const float* __restrict__ enc, float* __restrict__ out) {
  int bid = blockIdx.x, t = threadIdx.x;
  float inv = 1.f / psum[0];
  if (bid < 197) {
    int v = bid * 256 + t;
    if (v < VSZ) atomicAdd(&out[v], expf(score[v] - SHIFT) * inv);
  } else {
    __shared__ float pm[256];
    __shared__ int flag;
    if (t == 0) flag = 0;
    __syncthreads();
    int l0 = (bid - 197) * 256;
    int l = l0 + t;
    float p = expf(score[VSZ + l] - SHIFT) * inv;
    atomicAdd(&out[idx[l]], p);
    int matched = (idx[l] == din[0]);
    pm[t] = matched ? p : 0.f;
    if (matched) atomicExch(&flag, 1);
    __syncthreads();
    if (flag) {
      for (int h = t; h < HSZ; h += 256) {
        float s = 0.f;
        for (int l2 = 0; l2 < 256; ++l2)
          if (pm[l2] != 0.f) s = fmaf(pm[l2], enc[(size_t)(l0 + l2) * HSZ + h], s);
        if (s != 0.f) atomicAdd(&out[VSZ + HSZ + h], s);
      }
    }
  }
}

extern "C" void kernel_launch(void* const* d_in, const int* in_sizes, int n_in,
                              void* d_out, int out_size, void* d_ws, size_t ws_size,
                              hipStream_t stream) {
  const int*   din = (const int*)d_in[0];
  const float* h0  = (const float*)d_in[1];
  const float* enc = (const float*)d_in[2];
  const int*   idx = (const int*)d_in[3];
  const float* emb = (const float*)d_in[4];
  const float* Waw = (const float*)d_in[5];
  const float* baw = (const float*)d_in[6];
  const float* Wau = (const float*)d_in[7];
  const float* bau = (const float*)d_in[8];
  const float* Wih = (const float*)d_in[9];
  const float* bih = (const float*)d_in[10];
  const float* Whh = (const float*)d_in[11];
  const float* bhh = (const float*)d_in[12];
  const float* Wc  = (const float*)d_in[13];
  const float* bc  = (const float*)d_in[14];
  const float* Wg  = (const float*)d_in[15];
  const float* bg  = (const float*)d_in[16];
  float* out = (float*)d_out;
  float* ws  = (float*)d_ws;

  // ws layout (floats), 16B-aligned:
  float* acc    = ws;             // 1024
  float* rnn_in = ws + 1024;      // 1024
  float* gi     = ws + 2048;      // 3072 (+ gh at 5120)
  float* h_new  = ws + 8192;      // 1024
  float* attnw  = ws + 9216;      // 2048
  float* score  = ws + 11264;     // 52305 = [score_g | score_c]
  float* psum   = ws + 63616;     // 1
  unsigned short* bfbuf = (unsigned short*)(ws + 64000);  // enc bf16 (2097152) then Wc bf16 (1048576)
  unsigned short* encB = bfbuf;
  unsigned short* WcB  = bfbuf + 2097152;

  k_attn<<<1479, 256, 0, stream>>>(Waw, baw, din, emb, h0, enc, Wc, attnw, out,
                                   score + VSZ, acc, psum, bfbuf);
  k_attn_apply<<<128, 256, 0, stream>>>(attnw, enc, acc);
  k_rnn<<<256, 256, 0, stream>>>(Wau, bau, din, emb, acc, rnn_in);
  k_gates<<<1536, 256, 0, stream>>>(Wih, bih, rnn_in, Whh, bhh, h0, gi);
  k_gru<<<4, 256, 0, stream>>>(gi, gi + 3072, h0, h_new, out);
  k_huge<<<512 + (VSZ + 7) / 8, 256, 0, stream>>>(encB, WcB, bc, h0, Wg, bg, h_new, score);
  k_sum<<<64, 256, 0, stream>>>(score, psum);
  k_final<<<205, 256, 0, stream>>>(score, psum, idx, din, enc, out);
}